// Round 13
// baseline (246.579 us; speedup 1.0000x reference)
//
#include <hip/hip_runtime.h>
#include <hip/hip_bf16.h>

#define NN 10000
#define NE 160000
#define NET 170000   // edges + self loops
#define IN_DIM 512
#define D1 1024      // HEADS*HID
#define HEADS 4
#define HID 256
#define OUT_DIM 512
#define NEG_SLOPE 0.2f

typedef __attribute__((ext_vector_type(8))) short bf16x8;
typedef __attribute__((ext_vector_type(4))) float f32x4;

__device__ inline float b2f(unsigned short b) {
    union { unsigned u; float f; } x; x.u = ((unsigned)b) << 16; return x.f;
}
__device__ inline unsigned short f2b(float f) {
    union { float f; unsigned u; } x; x.f = f;
    unsigned u = x.u;
    unsigned r = u + 0x7FFFu + ((u >> 16) & 1u);
    return (unsigned short)(r >> 16);
}
__device__ inline float lrelu(float v) { return v > 0.f ? v : NEG_SLOPE * v; }

// int64 edge_index detect, per-thread inline: high dwords of first 16 values
// are all zero iff int64 (node ids < 2^31; P(16 random ids all 0) ~ 0).
__device__ inline bool is64(const int* ei32) {
    int acc = 0;
#pragma unroll
    for (int k = 0; k < 16; k++) acc |= ei32[2 * k + 1];
    return acc == 0;
}

__device__ inline void load_edge(const void* ei, bool f64, int e, int& s, int& d) {
    if (f64) {
        const long long* p = (const long long*)ei;
        s = (int)p[e]; d = (int)p[NE + e];
    } else {
        const int* p = (const int*)ei;
        s = p[e]; d = p[NE + e];
    }
}

// ---- zero counts/cursor (must precede count section of setup)
__global__ void zero_kernel(int* counts, int* cursor) {
    int i = blockIdx.x * blockDim.x + threadIdx.x;
    if (i < NN) { counts[i] = 0; cursor[i] = 0; }
}

// ---- scan body (prefix sum of counts -> indptr), one 256-thread block
__device__ void scan_dev(const int* counts, int* indptr) {
    __shared__ int part[256];
    int t = threadIdx.x;
    int base = t * 40;
    int local[40];
    int sum = 0;
#pragma unroll
    for (int k = 0; k < 40; k++) {
        int i = base + k;
        int c = (i < NN) ? counts[i] : 0;
        local[k] = sum;
        sum += c;
    }
    part[t] = sum;
    __syncthreads();
    for (int off = 1; off < 256; off <<= 1) {
        int v = (t >= off) ? part[t - off] : 0;
        __syncthreads();
        part[t] += v;
        __syncthreads();
    }
    int excl = part[t] - sum;
#pragma unroll
    for (int k = 0; k < 40; k++) {
        int i = base + k;
        if (i < NN) indptr[i] = excl + local[k];
    }
    if (t == 255) indptr[NN] = part[255];
}

// ---- setup: x->bf16 convert + 3 weight transposes + COUNT section
__device__ void tpose_tile(const float* __restrict__ in, unsigned short* __restrict__ out,
                           int R, int C, int bx, int by) {
    __shared__ float tile[32][33];
    int tx = threadIdx.x & 31, ty = threadIdx.x >> 5;
    int c = bx * 32 + tx;
#pragma unroll
    for (int r0 = 0; r0 < 32; r0 += 8) {
        int r = by * 32 + ty + r0;
        tile[ty + r0][tx] = in[(size_t)r * C + c];
    }
    __syncthreads();
    int oc = by * 32 + tx;
#pragma unroll
    for (int r0 = 0; r0 < 32; r0 += 8) {
        int orow = bx * 32 + ty + r0;
        out[(size_t)orow * R + oc] = f2b(tile[tx][ty + r0]);
    }
}

#define CVT_NB 5000   // NN*IN_DIM/4/256
#define TP1_NB 512    // (D1/32)*(IN_DIM/32)
#define TP2_NB 1024   // (D1/32)*(D1/32)
#define TP3_NB 512    // (OUT_DIM/32)*(D1/32)
#define CNT_NB 665    // ceil(NET/256)
__global__ __launch_bounds__(256) void setup_kernel(
    const void* ei, int* counts,
    const float* __restrict__ x, unsigned short* __restrict__ xb,
    const float* __restrict__ W1, unsigned short* __restrict__ W1t,
    const float* __restrict__ W2, unsigned short* __restrict__ W2t,
    const float* __restrict__ fcW, unsigned short* __restrict__ fcWt) {
    int b = blockIdx.x;
    if (b < CVT_NB) {
        int i = b * 256 + threadIdx.x;
        float4 v = reinterpret_cast<const float4*>(x)[i];
        ushort4 o;
        o.x = f2b(v.x); o.y = f2b(v.y); o.z = f2b(v.z); o.w = f2b(v.w);
        reinterpret_cast<ushort4*>(xb)[i] = o;
        return;
    }
    b -= CVT_NB;
    if (b < TP1_NB) { tpose_tile(W1, W1t, IN_DIM, D1, b & 31, b >> 5); return; }
    b -= TP1_NB;
    if (b < TP2_NB) { tpose_tile(W2, W2t, D1, D1, b & 31, b >> 5); return; }
    b -= TP2_NB;
    if (b < TP3_NB) { tpose_tile(fcW, fcWt, D1, OUT_DIM, b & 15, b >> 4); return; }
    b -= TP3_NB;
    // count section
    int e = b * 256 + threadIdx.x;
    if (e >= NET) return;
    bool f64 = is64((const int*)ei);
    int s, d;
    if (e < NE) load_edge(ei, f64, e, s, d);
    else d = e - NE;
    atomicAdd(&counts[d], 1);
}

// ---- C[M][N] = A[M][K](bf16) @ B[N][K](bf16)^T ; templated tile TBMxTBN,
// BK=64, 4 waves (2x2), global_load_lds width 16, XOR-swizzled LDS,
// bijective XCD-aware block swizzle (NWG param).
// COUNTED-VMCNT PIPELINE (T3/T4 minimum form): 3 LDS buffers, raw s_barrier
// (no vmcnt(0) drain), explicit s_waitcnt vmcnt(LPT) so the next tile's
// loads stay in flight across the barrier; issue tile k+2 right after the
// barrier into buffer (k-1)%3 (all readers of it passed the barrier).
// Blocks with blockIdx >= NWG run the CSR scan instead (fused launch).
template<int TBM, int TBN>
__global__ __launch_bounds__(256) void gemmT(
    const unsigned short* __restrict__ A, const unsigned short* __restrict__ B,
    const float* __restrict__ bias, float* __restrict__ Cf, unsigned short* __restrict__ Cb,
    int M, int N, int K, int NB, int NWG,
    const int* __restrict__ sc_counts, int* __restrict__ sc_indptr) {
    if ((int)blockIdx.x >= NWG) { scan_dev(sc_counts, sc_indptr); return; }
    constexpr int FM = TBM / 32;
    constexpr int FN = TBN / 32;
    constexpr int AISS = TBM / 32;   // 4KB staging issues for A per tile
    constexpr int BISS = TBN / 32;
    constexpr int ABUF = TBM * 64;   // shorts per buffer
    constexpr int BBUF = TBN * 64;
    __shared__ __align__(16) unsigned short As[3 * ABUF];
    __shared__ __align__(16) unsigned short Bs[3 * BBUF];
    int t = threadIdx.x;
    int q = NWG >> 3, r = NWG & 7;
    int xcd = blockIdx.x & 7, jj = blockIdx.x >> 3;
    int wg = (xcd < r ? xcd * (q + 1) : r * (q + 1) + (xcd - r) * q) + jj;
    int row0 = (wg / NB) * TBM, col0 = (wg % NB) * TBN;

    int w = t >> 6, l = t & 63;
    int wr = w >> 1, wc = w & 1;
    f32x4 acc[FM][FN] = {};

    int srow = w * 8 + (l >> 3);
    int scs = ((l & 7) ^ (l >> 3)) * 8;          // inverse-swizzled source col
    const unsigned short* ap[AISS];
    const unsigned short* bp[BISS];
#pragma unroll
    for (int i = 0; i < AISS; i++)
        ap[i] = A + (size_t)min(row0 + i * 32 + srow, M - 1) * K + scs;
#pragma unroll
    for (int i = 0; i < BISS; i++)
        bp[i] = B + (size_t)(col0 + i * 32 + srow) * K + scs;

    int rr = l & 15;
    int rb = (rr & 7) << 4;
    int kb0 = (l >> 4) << 4;
    int c_l = l & 15, r_h = (l >> 4) * 4;

#define GLD(src, dst) __builtin_amdgcn_global_load_lds( \
        (const __attribute__((address_space(1))) void*)(src), \
        (__attribute__((address_space(3))) void*)(dst), 16, 0, 0)
#define ISSUE_TILE(buf) do { \
        _Pragma("unroll") \
        for (int i = 0; i < AISS; i++) { \
            GLD(ap[i], As + (buf) * ABUF + i * 2048 + w * 512); ap[i] += 64; } \
        _Pragma("unroll") \
        for (int i = 0; i < BISS; i++) { \
            GLD(bp[i], Bs + (buf) * BBUF + i * 2048 + w * 512); bp[i] += 64; } \
    } while (0)

    int nt = K >> 6;   // >= 8 for all our shapes
    ISSUE_TILE(0);
    ISSUE_TILE(1);

    int cur = 0;
    for (int k = 0; k < nt; k++) {
        if (k < nt - 1) {
            if constexpr (AISS + BISS == 6)
                asm volatile("s_waitcnt vmcnt(6)" ::: "memory");
            else
                asm volatile("s_waitcnt vmcnt(4)" ::: "memory");
        } else {
            asm volatile("s_waitcnt vmcnt(0)" ::: "memory");
        }
        __builtin_amdgcn_s_barrier();
        if (k + 2 < nt) {
            int prv = cur - 1; if (prv < 0) prv = 2;   // == (k+2)%3
            ISSUE_TILE(prv);
        }
        const char* Ab = (const char*)(As + cur * ABUF);
        const char* Bb = (const char*)(Bs + cur * BBUF);
#pragma unroll
        for (int ks = 0; ks < 2; ks++) {
            int kb = ((ks << 6) | kb0) ^ rb;
            bf16x8 af[FM], bfv[FN];
#pragma unroll
            for (int mi = 0; mi < FM; mi++)
                af[mi] = *reinterpret_cast<const bf16x8*>(
                    Ab + (wr * (TBM / 2) + mi * 16 + rr) * 128 + kb);
#pragma unroll
            for (int ni = 0; ni < FN; ni++)
                bfv[ni] = *reinterpret_cast<const bf16x8*>(
                    Bb + (wc * (TBN / 2) + ni * 16 + rr) * 128 + kb);
#pragma unroll
            for (int mi = 0; mi < FM; mi++)
#pragma unroll
                for (int ni = 0; ni < FN; ni++)
                    acc[mi][ni] = __builtin_amdgcn_mfma_f32_16x16x32_bf16(
                        af[mi], bfv[ni], acc[mi][ni], 0, 0, 0);
        }
        cur = (cur == 2) ? 0 : cur + 1;
    }
#undef ISSUE_TILE
#undef GLD

    // C/D: col = lane&15, row = (lane>>4)*4 + j
#pragma unroll
    for (int mi = 0; mi < FM; mi++)
#pragma unroll
        for (int ni = 0; ni < FN; ni++) {
            int gc = col0 + wc * (TBN / 2) + ni * 16 + c_l;
#pragma unroll
            for (int j = 0; j < 4; j++) {
                int gr = row0 + wr * (TBM / 2) + mi * 16 + r_h + j;
                if (gr < M) {
                    float v = acc[mi][ni][j];
                    if (bias) v += bias[gc];
                    if (Cf) Cf[(size_t)gr * N + gc] = v;
                    if (Cb) Cb[(size_t)gr * N + gc] = f2b(v);
                }
            }
        }
}

// ---- att dots (wave-per-node) + fused CSR fill section (blocks >= NATT)
__global__ __launch_bounds__(256) void att_fill_kernel(
    const unsigned short* __restrict__ hb,
    const float* __restrict__ att_s, const float* __restrict__ att_d,
    float* __restrict__ aS, float* __restrict__ aD,
    const void* ei, const int* __restrict__ indptr,
    int* __restrict__ cursor, int* __restrict__ csr_src, int NATT) {
    if ((int)blockIdx.x >= NATT) {
        int e = ((int)blockIdx.x - NATT) * 256 + threadIdx.x;
        if (e >= NET) return;
        bool f64 = is64((const int*)ei);
        int s, d;
        if (e < NE) load_edge(ei, f64, e, s, d);
        else { s = e - NE; d = s; }
        int pos = indptr[d] + atomicAdd(&cursor[d], 1);
        csr_src[pos] = s;
        return;
    }
    int node = blockIdx.x * 4 + (threadIdx.x >> 6);
    int l = threadIdx.x & 63;
    int head = l >> 4, qq = l & 15;
    const unsigned short* hrow = hb + (size_t)node * D1 + head * HID + qq * 16;
    bf16x8 h0 = *reinterpret_cast<const bf16x8*>(hrow);
    bf16x8 h1 = *reinterpret_cast<const bf16x8*>(hrow + 8);
    const float* asp = att_s + head * HID + qq * 16;
    const float* adp = att_d + head * HID + qq * 16;
    float ps = 0.f, pd = 0.f;
#pragma unroll
    for (int c = 0; c < 8; c++) {
        float hv = b2f((unsigned short)h0[c]);
        float hw = b2f((unsigned short)h1[c]);
        ps += hv * asp[c] + hw * asp[8 + c];
        pd += hv * adp[c] + hw * adp[8 + c];
    }
#pragma unroll
    for (int off = 1; off <= 8; off <<= 1) {
        ps += __shfl_xor(ps, off);
        pd += __shfl_xor(pd, off);
    }
    if (qq == 0) {
        aS[node * HEADS + head] = ps;
        aD[node * HEADS + head] = pd;
    }
}

// ---- aggregation: wave-per-node, barrier-free, no LDS (best-known form;
// six structures converge at ~51us: per-CU outstanding-line (MSHR) floor
// for random 2KB row gathers -> treated as hardware wall).
__global__ __launch_bounds__(256) void agg_kernel(const unsigned short* __restrict__ hb,
                                                  const float* __restrict__ aS,
                                                  const float* __restrict__ aD,
                                                  const int* __restrict__ indptr,
                                                  const int* __restrict__ csr_src,
                                                  const float* __restrict__ bias,
                                                  unsigned short* __restrict__ outb) {
    int node = blockIdx.x * 4 + (threadIdx.x >> 6);
    int l = threadIdx.x & 63;
    int head = l >> 4;
    int beg = indptr[node];
    int deg = indptr[node + 1] - beg;
    float adst = aD[node * HEADS + head];
    const unsigned short* hp = hb + (size_t)l * 16;
    const int* cs = csr_src + beg;
    float acc[16];
#pragma unroll
    for (int c = 0; c < 16; c++) acc[c] = 0.f;
    float esum = 0.f;
    int dm = deg - 1;
    for (int j = 0; j < deg; j += 4) {
        int i0 = j, i1 = min(j + 1, dm), i2 = min(j + 2, dm), i3 = min(j + 3, dm);
        int s0 = cs[i0], s1 = cs[i1], s2 = cs[i2], s3 = cs[i3];
        const unsigned short* r0 = hp + (size_t)s0 * D1;
        const unsigned short* r1 = hp + (size_t)s1 * D1;
        const unsigned short* r2 = hp + (size_t)s2 * D1;
        const unsigned short* r3 = hp + (size_t)s3 * D1;
        bf16x8 r0a = *reinterpret_cast<const bf16x8*>(r0);
        bf16x8 r0b = *reinterpret_cast<const bf16x8*>(r0 + 8);
        bf16x8 r1a = *reinterpret_cast<const bf16x8*>(r1);
        bf16x8 r1b = *reinterpret_cast<const bf16x8*>(r1 + 8);
        bf16x8 r2a = *reinterpret_cast<const bf16x8*>(r2);
        bf16x8 r2b = *reinterpret_cast<const bf16x8*>(r2 + 8);
        bf16x8 r3a = *reinterpret_cast<const bf16x8*>(r3);
        bf16x8 r3b = *reinterpret_cast<const bf16x8*>(r3 + 8);
        float e0 = __expf(lrelu(aS[s0 * HEADS + head] + adst));
        float e1 = (j + 1 <= dm) ? __expf(lrelu(aS[s1 * HEADS + head] + adst)) : 0.f;
        float e2 = (j + 2 <= dm) ? __expf(lrelu(aS[s2 * HEADS + head] + adst)) : 0.f;
        float e3 = (j + 3 <= dm) ? __expf(lrelu(aS[s3 * HEADS + head] + adst)) : 0.f;
        esum += e0 + e1 + e2 + e3;
#pragma unroll
        for (int c = 0; c < 8; c++) {
            acc[c] += e0 * b2f((unsigned short)r0a[c]) + e1 * b2f((unsigned short)r1a[c])
                    + e2 * b2f((unsigned short)r2a[c]) + e3 * b2f((unsigned short)r3a[c]);
            acc[8 + c] += e0 * b2f((unsigned short)r0b[c]) + e1 * b2f((unsigned short)r1b[c])
                        + e2 * b2f((unsigned short)r2b[c]) + e3 * b2f((unsigned short)r3b[c]);
        }
    }
    float inv = 1.f / (esum + 1e-16f);
    const float* bp = bias + l * 16;
    bf16x8 o0, o1;
#pragma unroll
    for (int c = 0; c < 8; c++) {
        o0[c] = (short)f2b(fmaxf(acc[c] * inv + bp[c], 0.f));
        o1[c] = (short)f2b(fmaxf(acc[8 + c] * inv + bp[8 + c], 0.f));
    }
    unsigned short* op = outb + (size_t)node * D1 + l * 16;
    *reinterpret_cast<bf16x8*>(op) = o0;
    *reinterpret_cast<bf16x8*>(op + 8) = o1;
}

extern "C" void kernel_launch(void* const* d_in, const int* in_sizes, int n_in,
                              void* d_out, int out_size, void* d_ws, size_t ws_size,
                              hipStream_t stream) {
    const float* x   = (const float*)d_in[0];
    const void*  ei  = d_in[1];
    const float* W1  = (const float*)d_in[2];
    const float* as1 = (const float*)d_in[3];
    const float* ad1 = (const float*)d_in[4];
    const float* b1  = (const float*)d_in[5];
    const float* W2  = (const float*)d_in[6];
    const float* as2 = (const float*)d_in[7];
    const float* ad2 = (const float*)d_in[8];
    const float* b2  = (const float*)d_in[9];
    const float* fcW = (const float*)d_in[10];
    const float* fcb = (const float*)d_in[11];
    float* out = (float*)d_out;

    char* ws = (char*)d_ws;
    size_t o = 0;
    auto carve = [&](size_t bytes) -> char* {
        char* p = ws + o;
        o = (o + bytes + 255) & ~(size_t)255;
        return p;
    };
    unsigned short* xb   = (unsigned short*)carve((size_t)NN * IN_DIM * 2);
    unsigned short* hb   = (unsigned short*)carve((size_t)NN * D1 * 2);
    unsigned short* x2b  = (unsigned short*)carve((size_t)NN * D1 * 2);
    unsigned short* W1t  = (unsigned short*)carve((size_t)D1 * IN_DIM * 2);
    unsigned short* W2t  = (unsigned short*)carve((size_t)D1 * D1 * 2);
    unsigned short* fcWt = (unsigned short*)carve((size_t)OUT_DIM * D1 * 2);
    float* aS   = (float*)carve((size_t)NN * HEADS * 4);
    float* aD   = (float*)carve((size_t)NN * HEADS * 4);
    int* counts = (int*)carve((size_t)NN * 4);
    int* cursor = (int*)carve((size_t)NN * 4);
    int* indptr = (int*)carve((size_t)(NN + 1) * 4);
    int* csr_src= (int*)carve((size_t)NET * 4);
    (void)ws_size; (void)in_sizes; (void)n_in; (void)out_size;

    const int MB128 = (NN + 127) / 128;  // 79
    const int MB64  = (NN + 63) / 64;    // 157
    const int G1 = MB128 * (D1 / 64);    // 1264
    const int GF = MB64 * (OUT_DIM / 64);// 1256
    const int NATT = NN / 4;             // 2500

    // 1. zero counts/cursor
    zero_kernel<<<(NN + 255) / 256, 256, 0, stream>>>(counts, cursor);
    // 2. setup: cvt + transposes + CSR count
    setup_kernel<<<CVT_NB + TP1_NB + TP2_NB + TP3_NB + CNT_NB, 256, 0, stream>>>(
        ei, counts, x, xb, W1, W1t, W2, W2t, fcW, fcWt);
    // 3. gemm1 (+1 block: CSR scan)
    gemmT<128, 64><<<G1 + 1, 256, 0, stream>>>(xb, W1t, nullptr, nullptr, hb,
                                               NN, D1, IN_DIM, D1 / 64, G1,
                                               counts, indptr);
    // 4. att1 + CSR fill
    att_fill_kernel<<<NATT + CNT_NB, 256, 0, stream>>>(hb, as1, ad1, aS, aD,
                                                       ei, indptr, cursor, csr_src, NATT);
    // 5. agg1
    agg_kernel<<<NATT, 256, 0, stream>>>(hb, aS, aD, indptr, csr_src, b1, x2b);
    // 6. gemm2
    gemmT<128, 64><<<G1, 256, 0, stream>>>(x2b, W2t, nullptr, nullptr, hb,
                                           NN, D1, D1, D1 / 64, G1,
                                           nullptr, nullptr);
    // 7. att2
    att_fill_kernel<<<NATT, 256, 0, stream>>>(hb, as2, ad2, aS, aD,
                                              ei, indptr, cursor, csr_src, NATT);
    // 8. agg2
    agg_kernel<<<NATT, 256, 0, stream>>>(hb, aS, aD, indptr, csr_src, b2, x2b);
    // 9. final fc (bias, f32 out)
    gemmT<64, 64><<<GF, 256, 0, stream>>>(x2b, fcWt, fcb, out, nullptr,
                                          NN, OUT_DIM, D1, OUT_DIM / 64, GF,
                                          nullptr, nullptr);
}

// Round 14
// 229.928 us; speedup vs baseline: 1.0724x; 1.0724x over previous
//
#include <hip/hip_runtime.h>
#include <hip/hip_bf16.h>

#define NN 10000
#define NE 160000
#define NET 170000   // edges + self loops
#define IN_DIM 512
#define D1 1024      // HEADS*HID
#define HEADS 4
#define HID 256
#define OUT_DIM 512
#define NEG_SLOPE 0.2f

typedef __attribute__((ext_vector_type(8))) short bf16x8;
typedef __attribute__((ext_vector_type(4))) float f32x4;

__device__ inline float b2f(unsigned short b) {
    union { unsigned u; float f; } x; x.u = ((unsigned)b) << 16; return x.f;
}
__device__ inline unsigned short f2b(float f) {
    union { float f; unsigned u; } x; x.f = f;
    unsigned u = x.u;
    unsigned r = u + 0x7FFFu + ((u >> 16) & 1u);
    return (unsigned short)(r >> 16);
}
__device__ inline float lrelu(float v) { return v > 0.f ? v : NEG_SLOPE * v; }

// int64 edge_index detect, per-thread inline: high dwords of first 16 values
// are all zero iff int64 (node ids < 2^31; P(16 random ids all 0) ~ 0).
__device__ inline bool is64(const int* ei32) {
    int acc = 0;
#pragma unroll
    for (int k = 0; k < 16; k++) acc |= ei32[2 * k + 1];
    return acc == 0;
}

__device__ inline void load_edge(const void* ei, bool f64, int e, int& s, int& d) {
    if (f64) {
        const long long* p = (const long long*)ei;
        s = (int)p[e]; d = (int)p[NE + e];
    } else {
        const int* p = (const int*)ei;
        s = p[e]; d = p[NE + e];
    }
}

// ---- zero counts/cursor (must precede count section of setup)
__global__ void zero_kernel(int* counts, int* cursor) {
    int i = blockIdx.x * blockDim.x + threadIdx.x;
    if (i < NN) { counts[i] = 0; cursor[i] = 0; }
}

// ---- scan body (prefix sum of counts -> indptr), one 256-thread block
__device__ void scan_dev(const int* counts, int* indptr) {
    __shared__ int part[256];
    int t = threadIdx.x;
    int base = t * 40;
    int local[40];
    int sum = 0;
#pragma unroll
    for (int k = 0; k < 40; k++) {
        int i = base + k;
        int c = (i < NN) ? counts[i] : 0;
        local[k] = sum;
        sum += c;
    }
    part[t] = sum;
    __syncthreads();
    for (int off = 1; off < 256; off <<= 1) {
        int v = (t >= off) ? part[t - off] : 0;
        __syncthreads();
        part[t] += v;
        __syncthreads();
    }
    int excl = part[t] - sum;
#pragma unroll
    for (int k = 0; k < 40; k++) {
        int i = base + k;
        if (i < NN) indptr[i] = excl + local[k];
    }
    if (t == 255) indptr[NN] = part[255];
}

// ---- setup: x->bf16 convert + 3 weight transposes + COUNT section
__device__ void tpose_tile(const float* __restrict__ in, unsigned short* __restrict__ out,
                           int R, int C, int bx, int by) {
    __shared__ float tile[32][33];
    int tx = threadIdx.x & 31, ty = threadIdx.x >> 5;
    int c = bx * 32 + tx;
#pragma unroll
    for (int r0 = 0; r0 < 32; r0 += 8) {
        int r = by * 32 + ty + r0;
        tile[ty + r0][tx] = in[(size_t)r * C + c];
    }
    __syncthreads();
    int oc = by * 32 + tx;
#pragma unroll
    for (int r0 = 0; r0 < 32; r0 += 8) {
        int orow = bx * 32 + ty + r0;
        out[(size_t)orow * R + oc] = f2b(tile[tx][ty + r0]);
    }
}

#define CVT_NB 5000   // NN*IN_DIM/4/256
#define TP1_NB 512    // (D1/32)*(IN_DIM/32)
#define TP2_NB 1024   // (D1/32)*(D1/32)
#define TP3_NB 512    // (OUT_DIM/32)*(D1/32)
#define CNT_NB 665    // ceil(NET/256)
__global__ __launch_bounds__(256) void setup_kernel(
    const void* ei, int* counts,
    const float* __restrict__ x, unsigned short* __restrict__ xb,
    const float* __restrict__ W1, unsigned short* __restrict__ W1t,
    const float* __restrict__ W2, unsigned short* __restrict__ W2t,
    const float* __restrict__ fcW, unsigned short* __restrict__ fcWt) {
    int b = blockIdx.x;
    if (b < CVT_NB) {
        int i = b * 256 + threadIdx.x;
        float4 v = reinterpret_cast<const float4*>(x)[i];
        ushort4 o;
        o.x = f2b(v.x); o.y = f2b(v.y); o.z = f2b(v.z); o.w = f2b(v.w);
        reinterpret_cast<ushort4*>(xb)[i] = o;
        return;
    }
    b -= CVT_NB;
    if (b < TP1_NB) { tpose_tile(W1, W1t, IN_DIM, D1, b & 31, b >> 5); return; }
    b -= TP1_NB;
    if (b < TP2_NB) { tpose_tile(W2, W2t, D1, D1, b & 31, b >> 5); return; }
    b -= TP2_NB;
    if (b < TP3_NB) { tpose_tile(fcW, fcWt, D1, OUT_DIM, b & 15, b >> 4); return; }
    b -= TP3_NB;
    // count section
    int e = b * 256 + threadIdx.x;
    if (e >= NET) return;
    bool f64 = is64((const int*)ei);
    int s, d;
    if (e < NE) load_edge(ei, f64, e, s, d);
    else d = e - NE;
    atomicAdd(&counts[d], 1);
}

// ---- C[M][N] = A[M][K](bf16) @ B[N][K](bf16)^T ; templated tile TBMxTBN,
// BK=64, 4 waves (2x2), global_load_lds width 16, XOR-swizzled LDS,
// bijective XCD-aware block swizzle (NWG param), double-buffered LDS
// (2-buffer form; counted-vmcnt 3-buffer variant regressed in r13 —
// occupancy loss beats pipeline gain on this tile family).
// Blocks with blockIdx >= NWG run the CSR scan instead (fused launch).
template<int TBM, int TBN>
__global__ __launch_bounds__(256) void gemmT(
    const unsigned short* __restrict__ A, const unsigned short* __restrict__ B,
    const float* __restrict__ bias, float* __restrict__ Cf, unsigned short* __restrict__ Cb,
    int M, int N, int K, int NB, int NWG,
    const int* __restrict__ sc_counts, int* __restrict__ sc_indptr) {
    if ((int)blockIdx.x >= NWG) { scan_dev(sc_counts, sc_indptr); return; }
    constexpr int FM = TBM / 32;
    constexpr int FN = TBN / 32;
    constexpr int AISS = TBM / 32;
    constexpr int BISS = TBN / 32;
    constexpr int ABUF = TBM * 64;
    constexpr int BBUF = TBN * 64;
    __shared__ __align__(16) unsigned short As[2 * ABUF];
    __shared__ __align__(16) unsigned short Bs[2 * BBUF];
    int t = threadIdx.x;
    int q = NWG >> 3, r = NWG & 7;
    int xcd = blockIdx.x & 7, jj = blockIdx.x >> 3;
    int wg = (xcd < r ? xcd * (q + 1) : r * (q + 1) + (xcd - r) * q) + jj;
    int row0 = (wg / NB) * TBM, col0 = (wg % NB) * TBN;

    int w = t >> 6, l = t & 63;
    int wr = w >> 1, wc = w & 1;
    f32x4 acc[FM][FN] = {};

    int srow = w * 8 + (l >> 3);
    int scs = ((l & 7) ^ (l >> 3)) * 8;          // inverse-swizzled source col
    const unsigned short* ap[AISS];
    const unsigned short* bp[BISS];
#pragma unroll
    for (int i = 0; i < AISS; i++)
        ap[i] = A + (size_t)min(row0 + i * 32 + srow, M - 1) * K + scs;
#pragma unroll
    for (int i = 0; i < BISS; i++)
        bp[i] = B + (size_t)(col0 + i * 32 + srow) * K + scs;

    int rr = l & 15;
    int rb = (rr & 7) << 4;
    int kb0 = (l >> 4) << 4;
    int c_l = l & 15, r_h = (l >> 4) * 4;

#define GLD(src, dst) __builtin_amdgcn_global_load_lds( \
        (const __attribute__((address_space(1))) void*)(src), \
        (__attribute__((address_space(3))) void*)(dst), 16, 0, 0)

#pragma unroll
    for (int i = 0; i < AISS; i++) { GLD(ap[i], As + i * 2048 + w * 512); ap[i] += 64; }
#pragma unroll
    for (int i = 0; i < BISS; i++) { GLD(bp[i], Bs + i * 2048 + w * 512); bp[i] += 64; }
    __syncthreads();

    int cur = 0;
    for (int k0 = 0; k0 < K; k0 += 64) {
        int nxt = cur ^ 1;
        if (k0 + 64 < K) {
#pragma unroll
            for (int i = 0; i < AISS; i++) {
                GLD(ap[i], As + nxt * ABUF + i * 2048 + w * 512);
                ap[i] += 64;
            }
#pragma unroll
            for (int i = 0; i < BISS; i++) {
                GLD(bp[i], Bs + nxt * BBUF + i * 2048 + w * 512);
                bp[i] += 64;
            }
        }
        const char* Ab = (const char*)(As + cur * ABUF);
        const char* Bb = (const char*)(Bs + cur * BBUF);
#pragma unroll
        for (int ks = 0; ks < 2; ks++) {
            int kb = ((ks << 6) | kb0) ^ rb;
            bf16x8 af[FM], bfv[FN];
#pragma unroll
            for (int mi = 0; mi < FM; mi++)
                af[mi] = *reinterpret_cast<const bf16x8*>(
                    Ab + (wr * (TBM / 2) + mi * 16 + rr) * 128 + kb);
#pragma unroll
            for (int ni = 0; ni < FN; ni++)
                bfv[ni] = *reinterpret_cast<const bf16x8*>(
                    Bb + (wc * (TBN / 2) + ni * 16 + rr) * 128 + kb);
#pragma unroll
            for (int mi = 0; mi < FM; mi++)
#pragma unroll
                for (int ni = 0; ni < FN; ni++)
                    acc[mi][ni] = __builtin_amdgcn_mfma_f32_16x16x32_bf16(
                        af[mi], bfv[ni], acc[mi][ni], 0, 0, 0);
        }
        __syncthreads();
        cur = nxt;
    }
#undef GLD

    // C/D: col = lane&15, row = (lane>>4)*4 + j
#pragma unroll
    for (int mi = 0; mi < FM; mi++)
#pragma unroll
        for (int ni = 0; ni < FN; ni++) {
            int gc = col0 + wc * (TBN / 2) + ni * 16 + c_l;
#pragma unroll
            for (int j = 0; j < 4; j++) {
                int gr = row0 + wr * (TBM / 2) + mi * 16 + r_h + j;
                if (gr < M) {
                    float v = acc[mi][ni][j];
                    if (bias) v += bias[gc];
                    if (Cf) Cf[(size_t)gr * N + gc] = v;
                    if (Cb) Cb[(size_t)gr * N + gc] = f2b(v);
                }
            }
        }
}

// ---- att dots (wave-per-node) + fused CSR fill section (blocks >= NATT)
__global__ __launch_bounds__(256) void att_fill_kernel(
    const unsigned short* __restrict__ hb,
    const float* __restrict__ att_s, const float* __restrict__ att_d,
    float* __restrict__ aS, float* __restrict__ aD,
    const void* ei, const int* __restrict__ indptr,
    int* __restrict__ cursor, int* __restrict__ csr_src, int NATT) {
    if ((int)blockIdx.x >= NATT) {
        int e = ((int)blockIdx.x - NATT) * 256 + threadIdx.x;
        if (e >= NET) return;
        bool f64 = is64((const int*)ei);
        int s, d;
        if (e < NE) load_edge(ei, f64, e, s, d);
        else { s = e - NE; d = s; }
        int pos = indptr[d] + atomicAdd(&cursor[d], 1);
        csr_src[pos] = s;
        return;
    }
    int node = blockIdx.x * 4 + (threadIdx.x >> 6);
    int l = threadIdx.x & 63;
    int head = l >> 4, qq = l & 15;
    const unsigned short* hrow = hb + (size_t)node * D1 + head * HID + qq * 16;
    bf16x8 h0 = *reinterpret_cast<const bf16x8*>(hrow);
    bf16x8 h1 = *reinterpret_cast<const bf16x8*>(hrow + 8);
    const float* asp = att_s + head * HID + qq * 16;
    const float* adp = att_d + head * HID + qq * 16;
    float ps = 0.f, pd = 0.f;
#pragma unroll
    for (int c = 0; c < 8; c++) {
        float hv = b2f((unsigned short)h0[c]);
        float hw = b2f((unsigned short)h1[c]);
        ps += hv * asp[c] + hw * asp[8 + c];
        pd += hv * adp[c] + hw * adp[8 + c];
    }
#pragma unroll
    for (int off = 1; off <= 8; off <<= 1) {
        ps += __shfl_xor(ps, off);
        pd += __shfl_xor(pd, off);
    }
    if (qq == 0) {
        aS[node * HEADS + head] = ps;
        aD[node * HEADS + head] = pd;
    }
}

// ---- aggregation: wave-per-node, barrier-free, no LDS (best-known form;
// six structures converge at ~51us: per-CU outstanding-line (MSHR) floor
// for random 2KB row gathers -> treated as hardware wall).
__global__ __launch_bounds__(256) void agg_kernel(const unsigned short* __restrict__ hb,
                                                  const float* __restrict__ aS,
                                                  const float* __restrict__ aD,
                                                  const int* __restrict__ indptr,
                                                  const int* __restrict__ csr_src,
                                                  const float* __restrict__ bias,
                                                  unsigned short* __restrict__ outb) {
    int node = blockIdx.x * 4 + (threadIdx.x >> 6);
    int l = threadIdx.x & 63;
    int head = l >> 4;
    int beg = indptr[node];
    int deg = indptr[node + 1] - beg;
    float adst = aD[node * HEADS + head];
    const unsigned short* hp = hb + (size_t)l * 16;
    const int* cs = csr_src + beg;
    float acc[16];
#pragma unroll
    for (int c = 0; c < 16; c++) acc[c] = 0.f;
    float esum = 0.f;
    int dm = deg - 1;
    for (int j = 0; j < deg; j += 4) {
        int i0 = j, i1 = min(j + 1, dm), i2 = min(j + 2, dm), i3 = min(j + 3, dm);
        int s0 = cs[i0], s1 = cs[i1], s2 = cs[i2], s3 = cs[i3];
        const unsigned short* r0 = hp + (size_t)s0 * D1;
        const unsigned short* r1 = hp + (size_t)s1 * D1;
        const unsigned short* r2 = hp + (size_t)s2 * D1;
        const unsigned short* r3 = hp + (size_t)s3 * D1;
        bf16x8 r0a = *reinterpret_cast<const bf16x8*>(r0);
        bf16x8 r0b = *reinterpret_cast<const bf16x8*>(r0 + 8);
        bf16x8 r1a = *reinterpret_cast<const bf16x8*>(r1);
        bf16x8 r1b = *reinterpret_cast<const bf16x8*>(r1 + 8);
        bf16x8 r2a = *reinterpret_cast<const bf16x8*>(r2);
        bf16x8 r2b = *reinterpret_cast<const bf16x8*>(r2 + 8);
        bf16x8 r3a = *reinterpret_cast<const bf16x8*>(r3);
        bf16x8 r3b = *reinterpret_cast<const bf16x8*>(r3 + 8);
        float e0 = __expf(lrelu(aS[s0 * HEADS + head] + adst));
        float e1 = (j + 1 <= dm) ? __expf(lrelu(aS[s1 * HEADS + head] + adst)) : 0.f;
        float e2 = (j + 2 <= dm) ? __expf(lrelu(aS[s2 * HEADS + head] + adst)) : 0.f;
        float e3 = (j + 3 <= dm) ? __expf(lrelu(aS[s3 * HEADS + head] + adst)) : 0.f;
        esum += e0 + e1 + e2 + e3;
#pragma unroll
        for (int c = 0; c < 8; c++) {
            acc[c] += e0 * b2f((unsigned short)r0a[c]) + e1 * b2f((unsigned short)r1a[c])
                    + e2 * b2f((unsigned short)r2a[c]) + e3 * b2f((unsigned short)r3a[c]);
            acc[8 + c] += e0 * b2f((unsigned short)r0b[c]) + e1 * b2f((unsigned short)r1b[c])
                        + e2 * b2f((unsigned short)r2b[c]) + e3 * b2f((unsigned short)r3b[c]);
        }
    }
    float inv = 1.f / (esum + 1e-16f);
    const float* bp = bias + l * 16;
    bf16x8 o0, o1;
#pragma unroll
    for (int c = 0; c < 8; c++) {
        o0[c] = (short)f2b(fmaxf(acc[c] * inv + bp[c], 0.f));
        o1[c] = (short)f2b(fmaxf(acc[8 + c] * inv + bp[8 + c], 0.f));
    }
    unsigned short* op = outb + (size_t)node * D1 + l * 16;
    *reinterpret_cast<bf16x8*>(op) = o0;
    *reinterpret_cast<bf16x8*>(op + 8) = o1;
}

extern "C" void kernel_launch(void* const* d_in, const int* in_sizes, int n_in,
                              void* d_out, int out_size, void* d_ws, size_t ws_size,
                              hipStream_t stream) {
    const float* x   = (const float*)d_in[0];
    const void*  ei  = d_in[1];
    const float* W1  = (const float*)d_in[2];
    const float* as1 = (const float*)d_in[3];
    const float* ad1 = (const float*)d_in[4];
    const float* b1  = (const float*)d_in[5];
    const float* W2  = (const float*)d_in[6];
    const float* as2 = (const float*)d_in[7];
    const float* ad2 = (const float*)d_in[8];
    const float* b2  = (const float*)d_in[9];
    const float* fcW = (const float*)d_in[10];
    const float* fcb = (const float*)d_in[11];
    float* out = (float*)d_out;

    char* ws = (char*)d_ws;
    size_t o = 0;
    auto carve = [&](size_t bytes) -> char* {
        char* p = ws + o;
        o = (o + bytes + 255) & ~(size_t)255;
        return p;
    };
    unsigned short* xb   = (unsigned short*)carve((size_t)NN * IN_DIM * 2);
    unsigned short* hb   = (unsigned short*)carve((size_t)NN * D1 * 2);
    unsigned short* x2b  = (unsigned short*)carve((size_t)NN * D1 * 2);
    unsigned short* W1t  = (unsigned short*)carve((size_t)D1 * IN_DIM * 2);
    unsigned short* W2t  = (unsigned short*)carve((size_t)D1 * D1 * 2);
    unsigned short* fcWt = (unsigned short*)carve((size_t)OUT_DIM * D1 * 2);
    float* aS   = (float*)carve((size_t)NN * HEADS * 4);
    float* aD   = (float*)carve((size_t)NN * HEADS * 4);
    int* counts = (int*)carve((size_t)NN * 4);
    int* cursor = (int*)carve((size_t)NN * 4);
    int* indptr = (int*)carve((size_t)(NN + 1) * 4);
    int* csr_src= (int*)carve((size_t)NET * 4);
    (void)ws_size; (void)in_sizes; (void)n_in; (void)out_size;

    const int MB128 = (NN + 127) / 128;  // 79
    const int MB64  = (NN + 63) / 64;    // 157
    const int G1 = MB128 * (D1 / 64);    // 1264
    const int GF = MB64 * (OUT_DIM / 64);// 1256
    const int NATT = NN / 4;             // 2500

    // 1. zero counts/cursor
    zero_kernel<<<(NN + 255) / 256, 256, 0, stream>>>(counts, cursor);
    // 2. setup: cvt + transposes + CSR count
    setup_kernel<<<CVT_NB + TP1_NB + TP2_NB + TP3_NB + CNT_NB, 256, 0, stream>>>(
        ei, counts, x, xb, W1, W1t, W2, W2t, fcW, fcWt);
    // 3. gemm1 (+1 block: CSR scan)
    gemmT<128, 64><<<G1 + 1, 256, 0, stream>>>(xb, W1t, nullptr, nullptr, hb,
                                               NN, D1, IN_DIM, D1 / 64, G1,
                                               counts, indptr);
    // 4. att1 + CSR fill
    att_fill_kernel<<<NATT + CNT_NB, 256, 0, stream>>>(hb, as1, ad1, aS, aD,
                                                       ei, indptr, cursor, csr_src, NATT);
    // 5. agg1
    agg_kernel<<<NATT, 256, 0, stream>>>(hb, aS, aD, indptr, csr_src, b1, x2b);
    // 6. gemm2
    gemmT<128, 64><<<G1, 256, 0, stream>>>(x2b, W2t, nullptr, nullptr, hb,
                                           NN, D1, D1, D1 / 64, G1,
                                           nullptr, nullptr);
    // 7. att2
    att_fill_kernel<<<NATT, 256, 0, stream>>>(hb, as2, ad2, aS, aD,
                                              ei, indptr, cursor, csr_src, NATT);
    // 8. agg2
    agg_kernel<<<NATT, 256, 0, stream>>>(hb, aS, aD, indptr, csr_src, b2, x2b);
    // 9. final fc (bias, f32 out)
    gemmT<64, 64><<<GF, 256, 0, stream>>>(x2b, fcWt, fcb, out, nullptr,
                                          NN, OUT_DIM, D1, OUT_DIM / 64, GF,
                                          nullptr, nullptr);
}